// Round 1
// baseline (40.107 us; speedup 1.0000x reference)
//
#include <hip/hip_runtime.h>

#define B_ 16
#define C_ 3
#define H_ 224
#define W_ 224
#define STEPS_ 32
#define NIMG (B_ * C_)          // 48
#define STRIPS 8
#define ROWS_PER (H_ / STRIPS)  // 28
#define NBINS 33                // bins 0..31 real, bin 32 = "beyond t_max" (masked)

// smallest k in [0,32] with t_k >= x, where t_k = (float)k * fl(1/31)
// (replicates jnp.linspace(0,1,32) = iota * delta computed in f32)
__device__ __forceinline__ int bin_of(float x) {
    const float C = 1.0f / 31.0f;
    int k = (int)(x * 31.0f);
    if (k < 0) k = 0;
    if (k > 31) k = 31;
    while (k > 0 && (float)(k - 1) * C >= x) --k;
    while (k < 32 && (float)k * C < x) ++k;
    return k;
}

__global__ __launch_bounds__(256) void ecc_hist(const float* __restrict__ x,
                                                int* __restrict__ gh) {
    __shared__ unsigned char binS[(ROWS_PER + 1) * W_];  // 29*224 = 6496 B
    __shared__ int hist[4][NBINS];                       // per-wave histograms

    const int wg = blockIdx.x;
    const int img = wg >> 3;
    const int strip = wg & 7;
    const int tid = threadIdx.x;
    const int wave = tid >> 6;

    if (tid < 4 * NBINS) ((int*)hist)[tid] = 0;

    const int r0 = strip * ROWS_PER;
    const bool last = (strip == STRIPS - 1);
    const int nrows = ROWS_PER + (last ? 0 : 1);  // +1 halo row below

    // phase 1: global -> per-pixel bins in LDS (float4 loads, uchar4 stores)
    const float4* base4 =
        (const float4*)(x + (size_t)img * (H_ * W_) + (size_t)r0 * W_);
    uchar4* binS4 = (uchar4*)binS;
    const int n4 = nrows * (W_ / 4);
    for (int i = tid; i < n4; i += 256) {
        float4 v = base4[i];
        uchar4 b;
        b.x = (unsigned char)bin_of(v.x);
        b.y = (unsigned char)bin_of(v.y);
        b.z = (unsigned char)bin_of(v.z);
        b.w = (unsigned char)bin_of(v.w);
        binS4[i] = b;
    }
    __syncthreads();

    // phase 2: signed histogram of cell bins (cells owned by this strip)
    const int npix = ROWS_PER * W_;
    for (int i = tid; i < npix; i += 256) {
        const int row = i / W_;
        const int col = i - row * W_;
        const int b0 = binS[i];
        atomicAdd(&hist[wave][b0], 1);  // pixel, +1
        const bool hasR = (col < W_ - 1);
        const bool hasD = !(last && row == ROWS_PER - 1);
        int m01 = b0;
        if (hasR) {  // horizontal edge, -1
            m01 = max(b0, (int)binS[i + 1]);
            atomicAdd(&hist[wave][m01], -1);
        }
        if (hasD) {  // vertical edge, -1
            const int b2 = binS[i + W_];
            atomicAdd(&hist[wave][max(b0, b2)], -1);
            if (hasR) {  // square, +1
                const int b3 = binS[i + W_ + 1];
                atomicAdd(&hist[wave][max(m01, max(b2, b3))], 1);
            }
        }
    }
    __syncthreads();

    if (tid < NBINS) {
        const int s = hist[0][tid] + hist[1][tid] + hist[2][tid] + hist[3][tid];
        if (s != 0) atomicAdd(&gh[img * NBINS + tid], s);
    }
}

__global__ __launch_bounds__(64) void ecc_final(const int* __restrict__ gh,
                                                float* __restrict__ out) {
    const int img = blockIdx.x;
    const int lane = threadIdx.x;
    if (lane < STEPS_) {
        int v = gh[img * NBINS + lane];
        // inclusive scan over 32 lanes
        for (int off = 1; off < STEPS_; off <<= 1) {
            int n = __shfl_up(v, off, 64);
            if (lane >= off) v += n;
        }
        out[img * STEPS_ + lane] = (float)v;
    }
}

extern "C" void kernel_launch(void* const* d_in, const int* in_sizes, int n_in,
                              void* d_out, int out_size, void* d_ws, size_t ws_size,
                              hipStream_t stream) {
    const float* x = (const float*)d_in[0];
    float* out = (float*)d_out;
    int* gh = (int*)d_ws;

    hipMemsetAsync(gh, 0, NIMG * NBINS * sizeof(int), stream);
    ecc_hist<<<NIMG * STRIPS, 256, 0, stream>>>(x, gh);
    ecc_final<<<NIMG, 64, 0, stream>>>(gh, out);
}

// Round 2
// 25.661 us; speedup vs baseline: 1.5629x; 1.5629x over previous
//
#include <hip/hip_runtime.h>

#define B_ 16
#define C_ 3
#define H_ 224
#define W_ 224
#define STEPS_ 32
#define NIMG (B_ * C_)          // 48
#define STRIPS 16
#define ROWS_PER (H_ / STRIPS)  // 14
#define NBINS 33                // bins 0..31 real, bin 32 = "beyond t_max" (masked)

// smallest k in [0,32] with t_k >= x, where t_k = (float)k * fl(1/31)
// (replicates jnp.linspace(0,1,32) = iota * delta computed in f32)
__device__ __forceinline__ int bin_of(float x) {
    const float C = 1.0f / 31.0f;
    int k = (int)(x * 31.0f);
    if (k < 0) k = 0;
    if (k > 31) k = 31;
    while (k > 0 && (float)(k - 1) * C >= x) --k;
    while (k < 32 && (float)k * C < x) ++k;
    return k;
}

__global__ __launch_bounds__(256) void ecc_hist(const float* __restrict__ x,
                                                int* __restrict__ gh) {
    __shared__ unsigned char binS[(ROWS_PER + 1) * W_];  // 15*224 = 3360 B
    __shared__ int hist[4][NBINS];                       // per-wave histograms

    const int wg = blockIdx.x;
    const int img = wg / STRIPS;
    const int strip = wg % STRIPS;
    const int tid = threadIdx.x;
    const int wave = tid >> 6;

    if (tid < 4 * NBINS) ((int*)hist)[tid] = 0;

    const int r0 = strip * ROWS_PER;
    const bool last = (strip == STRIPS - 1);
    const int nrows = ROWS_PER + (last ? 0 : 1);  // +1 halo row below

    // phase 1: global -> per-pixel bins in LDS (float4 loads, uchar4 stores)
    const float4* base4 =
        (const float4*)(x + (size_t)img * (H_ * W_) + (size_t)r0 * W_);
    uchar4* binS4 = (uchar4*)binS;
    const int n4 = nrows * (W_ / 4);
    for (int i = tid; i < n4; i += 256) {
        float4 v = base4[i];
        uchar4 b;
        b.x = (unsigned char)bin_of(v.x);
        b.y = (unsigned char)bin_of(v.y);
        b.z = (unsigned char)bin_of(v.z);
        b.w = (unsigned char)bin_of(v.w);
        binS4[i] = b;
    }
    __syncthreads();

    // phase 2: signed histogram of cell bins (cells owned by this strip)
    const int npix = ROWS_PER * W_;
    for (int i = tid; i < npix; i += 256) {
        const int row = i / W_;
        const int col = i - row * W_;
        const int b0 = binS[i];
        atomicAdd(&hist[wave][b0], 1);  // pixel, +1
        const bool hasR = (col < W_ - 1);
        const bool hasD = !(last && row == ROWS_PER - 1);
        int m01 = b0;
        if (hasR) {  // horizontal edge, -1
            m01 = max(b0, (int)binS[i + 1]);
            atomicAdd(&hist[wave][m01], -1);
        }
        if (hasD) {  // vertical edge, -1
            const int b2 = binS[i + W_];
            atomicAdd(&hist[wave][max(b0, b2)], -1);
            if (hasR) {  // square, +1
                const int b3 = binS[i + W_ + 1];
                atomicAdd(&hist[wave][max(m01, max(b2, b3))], 1);
            }
        }
    }
    __syncthreads();

    // plain store of the full per-strip histogram (overwrites poisoned ws)
    if (tid < NBINS) {
        gh[wg * NBINS + tid] =
            hist[0][tid] + hist[1][tid] + hist[2][tid] + hist[3][tid];
    }
}

__global__ __launch_bounds__(64) void ecc_final(const int* __restrict__ gh,
                                                float* __restrict__ out) {
    const int img = blockIdx.x;
    const int lane = threadIdx.x;
    if (lane < STEPS_) {
        int v = 0;
        const int* base = gh + img * STRIPS * NBINS + lane;
#pragma unroll
        for (int s = 0; s < STRIPS; ++s) v += base[s * NBINS];
        // inclusive scan over 32 lanes
        for (int off = 1; off < STEPS_; off <<= 1) {
            int n = __shfl_up(v, off, 64);
            if (lane >= off) v += n;
        }
        out[img * STEPS_ + lane] = (float)v;
    }
}

extern "C" void kernel_launch(void* const* d_in, const int* in_sizes, int n_in,
                              void* d_out, int out_size, void* d_ws, size_t ws_size,
                              hipStream_t stream) {
    const float* x = (const float*)d_in[0];
    float* out = (float*)d_out;
    int* gh = (int*)d_ws;

    ecc_hist<<<NIMG * STRIPS, 256, 0, stream>>>(x, gh);
    ecc_final<<<NIMG, 64, 0, stream>>>(gh, out);
}

// Round 3
// 12.565 us; speedup vs baseline: 3.1919x; 2.0423x over previous
//
#include <hip/hip_runtime.h>

#define H_ 224
#define W_ 224
#define NIMG 48
#define NBINS 33          // bins 0..31 real; bin 32 = beyond t_max (ignored)
#define JOBS_PER_IMG 112  // 28 row-groups (8 rows each) x 4 col-groups (63 cols each)
#define NBLK (NIMG * JOBS_PER_IMG / 4)  // 1344 blocks, 4 wave-jobs per block
#define BLKS_PER_IMG (JOBS_PER_IMG / 4) // 28

// smallest k in [0,32] with k * fl(1/31) >= x  (== searchsorted(linspace(0,1,32), x, 'left'))
__device__ __forceinline__ int bin_of(float x) {
    const float C = 1.0f / 31.0f;
    int k = (int)__builtin_ceilf(x * 31.0f);
    k = min(k, 32);
    if ((float)(k - 1) * C >= x) --k;          // k==0: (-1)*C >= x>=0 is false, safe
    else if ((float)k * C < x) ++k;
    return k;
}

__global__ __launch_bounds__(256) void ecc_hist(const float* __restrict__ x,
                                                int* __restrict__ gh) {
    __shared__ int hist[4][NBINS];
    const int tid = threadIdx.x;
    const int wave = tid >> 6;
    const int lane = tid & 63;

    // each wave inits its own histogram: same-wave LDS ordering, no barrier needed
    if (lane < NBINS) hist[wave][lane] = 0;

    const int job  = blockIdx.x * 4 + wave;
    const int img  = job / JOBS_PER_IMG;
    const int jj   = job % JOBS_PER_IMG;
    const int rowg = jj >> 2;
    const int colg = jj & 3;
    const int col  = colg * 63 + lane;          // 1-col halo overlap between groups
    const bool produce = (lane < 63) && (col < W_);
    const bool hasR    = produce && (col < W_ - 1);
    const int  colc    = min(col, W_ - 1);      // clamp inactive lanes' loads

    const float* base = x + (size_t)img * (H_ * W_) + (size_t)(rowg * 8) * W_ + colc;
    int* hw = hist[wave];

    int bcur = bin_of(base[0]);
    const int r0 = rowg * 8;

#pragma unroll
    for (int ri = 0; ri < 8; ++ri) {
        const bool hasD = (r0 + ri < H_ - 1);   // wave-uniform
        int bnext = hasD ? bin_of(base[(ri + 1) * W_]) : 0;
        int sh = __shfl_down(bcur | (bnext << 16), 1, 64);
        int bR = sh & 0xffff, bDR = sh >> 16;
        if (hasD) {
            int e1 = max(bcur, bR);
            int e2 = max(bcur, bnext);
            if (hasR) {
                int lo = min(e1, e2), hi = max(e1, e2);
                int sq = max(hi, bDR);
                if (bcur != lo) { atomicAdd(&hw[bcur], 1); atomicAdd(&hw[lo], -1); }
                if (sq != hi)   { atomicAdd(&hw[sq], 1);   atomicAdd(&hw[hi], -1); }
            } else if (produce) {               // col 223: pixel + v-edge only
                if (bcur != e2) { atomicAdd(&hw[bcur], 1); atomicAdd(&hw[e2], -1); }
            }
        } else {                                // last row: pixel + h-edge only
            int e1 = max(bcur, bR);
            if (hasR) {
                if (bcur != e1) { atomicAdd(&hw[bcur], 1); atomicAdd(&hw[e1], -1); }
            } else if (produce) {               // bottom-right corner
                atomicAdd(&hw[bcur], 1);
            }
        }
        bcur = bnext;
    }
    __syncthreads();

    if (tid < NBINS) {
        gh[blockIdx.x * NBINS + tid] =
            hist[0][tid] + hist[1][tid] + hist[2][tid] + hist[3][tid];
    }
}

__global__ __launch_bounds__(64) void ecc_final(const int* __restrict__ gh,
                                                float* __restrict__ out) {
    const int img = blockIdx.x;
    const int lane = threadIdx.x;
    if (lane < 32) {
        int v = 0;
        const int* base = gh + img * BLKS_PER_IMG * NBINS + lane;
#pragma unroll
        for (int s = 0; s < BLKS_PER_IMG; ++s) v += base[s * NBINS];
        for (int off = 1; off < 32; off <<= 1) {
            int n = __shfl_up(v, off, 64);
            if (lane >= off) v += n;
        }
        out[img * 32 + lane] = (float)v;
    }
}

extern "C" void kernel_launch(void* const* d_in, const int* in_sizes, int n_in,
                              void* d_out, int out_size, void* d_ws, size_t ws_size,
                              hipStream_t stream) {
    const float* x = (const float*)d_in[0];
    float* out = (float*)d_out;
    int* gh = (int*)d_ws;

    ecc_hist<<<NBLK, 256, 0, stream>>>(x, gh);
    ecc_final<<<NIMG, 64, 0, stream>>>(gh, out);
}